// Round 1
// baseline (281.265 us; speedup 1.0000x reference)
//
#include <hip/hip_runtime.h>
#include <math.h>

#define LL 65536
#define DD 512
#define NH 4
#define HDIM 128

// ---------- workspace layout (float offsets) ----------
// 0     : q[512]
// 512   : qkg[4][512]            (scaled by 1/sqrt(128) and g1)
// 2560  : qkg_sum[4]
// 2564  : mxg[4]
// 2568  : inv_smg[4]
// 2572  : w2term[4]              (= W2_global / sm_global)
// 2576  : c[4][512]              context
// 4624  : o[512]                 attention output
// 5136  : y[512]                 residual row
// 5648  : m2, r2                 LN2 stats
// 5664  : h1[512]                MLP hidden
// 8192  : mx_b[256][4]
// 9216  : sm_b[256][4]
// 10240 : w2_b[256][4]
// 12288 : W1_b[256][2048]        per-block weighted-x partials
// total ~536576 floats (~2.05 MB)

__device__ __forceinline__ float dot4(float4 a, float4 b) {
    return a.x * b.x + a.y * b.y + a.z * b.z + a.w * b.w;
}
__device__ __forceinline__ float wred(float v) {
#pragma unroll
    for (int m = 32; m; m >>= 1) v += __shfl_xor(v, m, 64);
    return v;
}
__device__ __forceinline__ float4 f4fma(float4 acc, float s, float4 v) {
    acc.x += s * v.x; acc.y += s * v.y; acc.z += s * v.z; acc.w += s * v.w;
    return acc;
}
__device__ __forceinline__ float4 f4sfma(float4 acc, float c, float s, float4 v) {
    acc.x = acc.x * c + s * v.x; acc.y = acc.y * c + s * v.y;
    acc.z = acc.z * c + s * v.z; acc.w = acc.w * c + s * v.w;
    return acc;
}
__device__ __forceinline__ float4 f4scale(float4 a, float s) {
    a.x *= s; a.y *= s; a.z *= s; a.w *= s; return a;
}
__device__ __forceinline__ float4 lnrm4(float4 v, float m, float r, float4 g, float4 b) {
    float4 o;
    o.x = (v.x - m) * r * g.x + b.x; o.y = (v.y - m) * r * g.y + b.y;
    o.z = (v.z - m) * r * g.z + b.z; o.w = (v.w - m) * r * g.w + b.w;
    return o;
}

// ---------- A1: q[j] = dot(Wq[j], LN(x0)) + bq[j]   (wave per j) ----------
__global__ __launch_bounds__(256) void kA1(const float* __restrict__ x,
                                           const float* __restrict__ w_in,
                                           const float* __restrict__ b_in,
                                           const float* __restrict__ g1,
                                           const float* __restrict__ be1,
                                           float* __restrict__ ws) {
    int lane = threadIdx.x & 63;
    int j = blockIdx.x * 4 + (threadIdx.x >> 6);
    const float4* x4 = (const float4*)x;
    float4 a = x4[lane], b = x4[64 + lane];
    float ps = a.x + a.y + a.z + a.w + b.x + b.y + b.z + b.w;
    float pss = dot4(a, a) + dot4(b, b);
    ps = wred(ps); pss = wred(pss);
    float m = ps * (1.f / 512.f);
    float r = rsqrtf(pss * (1.f / 512.f) - m * m + 1e-5f);
    const float4* g4 = (const float4*)g1;
    const float4* bb4 = (const float4*)be1;
    float4 xna = lnrm4(a, m, r, g4[lane], bb4[lane]);
    float4 xnb = lnrm4(b, m, r, g4[64 + lane], bb4[64 + lane]);
    const float4* wr = (const float4*)(w_in + (size_t)j * DD);
    float acc = dot4(wr[lane], xna) + dot4(wr[64 + lane], xnb);
    acc = wred(acc);
    if (lane == 0) ws[j] = acc + b_in[j];
}

// ---------- A2: qkg[h][e] = (1/sqrt(128)) * (sum_d q[h,d]*Wk[h*128+d,e]) * g1[e] ----------
__global__ __launch_bounds__(512) void kA2(const float* __restrict__ w_in,
                                           const float* __restrict__ g1,
                                           float* __restrict__ ws) {
    __shared__ float qh[128];
    __shared__ float red[512];
    int h = blockIdx.x, tid = threadIdx.x;
    if (tid < 128) qh[tid] = ws[h * HDIM + tid];
    __syncthreads();
    const float* wk = w_in + (size_t)(DD + h * HDIM) * DD + tid;
    float acc = 0.f;
#pragma unroll 4
    for (int d = 0; d < HDIM; ++d) acc += qh[d] * wk[(size_t)d * DD];
    acc *= 0.088388347648318447f;  // 1/sqrt(128)
    float qg = acc * g1[tid];
    ws[512 + h * 512 + tid] = qg;
    red[tid] = qg;
    __syncthreads();
    for (int s = 256; s; s >>= 1) {
        if (tid < s) red[tid] += red[tid + s];
        __syncthreads();
    }
    if (tid == 0) ws[2560 + h] = red[0];
}

// ---------- B: streaming pass over x; online softmax + weighted-x accumulation ----------
__global__ __launch_bounds__(512) void kB(const float* __restrict__ x,
                                          float* __restrict__ ws) {
    __shared__ float lds[16384];  // 64 KB: [8][2048] wave regions; small stats alias the front
    int tid = threadIdx.x, lane = tid & 63, w = tid >> 6;
    const float4* qkg4 = (const float4*)(ws + 512);
    float4 qa[4], qb[4];
    float qs[4];
#pragma unroll
    for (int h = 0; h < 4; ++h) {
        qa[h] = qkg4[h * 128 + lane];
        qb[h] = qkg4[h * 128 + 64 + lane];
        qs[h] = ws[2560 + h];
    }
    float mx[4], sm[4], w2a[4];
    float4 Wa[4], Wb[4];
#pragma unroll
    for (int h = 0; h < 4; ++h) {
        mx[h] = -INFINITY; sm[h] = 0.f; w2a[h] = 0.f;
        Wa[h] = make_float4(0.f, 0.f, 0.f, 0.f);
        Wb[h] = make_float4(0.f, 0.f, 0.f, 0.f);
    }
    size_t row0 = ((size_t)blockIdx.x * 8 + w) * 32;
    const float4* xb = (const float4*)x + row0 * 128;
    for (int r = 0; r < 32; ++r) {
        float4 xa = xb[r * 128 + lane];
        float4 xc = xb[r * 128 + 64 + lane];
        float ps = xa.x + xa.y + xa.z + xa.w + xc.x + xc.y + xc.z + xc.w;
        float pss = dot4(xa, xa) + dot4(xc, xc);
        float p0 = dot4(xa, qa[0]) + dot4(xc, qb[0]);
        float p1 = dot4(xa, qa[1]) + dot4(xc, qb[1]);
        float p2 = dot4(xa, qa[2]) + dot4(xc, qb[2]);
        float p3 = dot4(xa, qa[3]) + dot4(xc, qb[3]);
        ps = wred(ps); pss = wred(pss);
        p0 = wred(p0); p1 = wred(p1); p2 = wred(p2); p3 = wred(p3);
        float m = ps * (1.f / 512.f);
        float rr = rsqrtf(pss * (1.f / 512.f) - m * m + 1e-5f);
        float rm = rr * m;
        float pd[4] = {p0, p1, p2, p3};
#pragma unroll
        for (int h = 0; h < 4; ++h) {
            float s = rr * pd[h] - rm * qs[h];
            if (s <= mx[h]) {            // wave-uniform branch (common path)
                float p = __expf(s - mx[h]);
                sm[h] += p;
                w2a[h] += p * rm;
                float pr = p * rr;
                Wa[h] = f4fma(Wa[h], pr, xa);
                Wb[h] = f4fma(Wb[h], pr, xc);
            } else {                     // new max: rescale accumulators
                float cc = __expf(mx[h] - s);
                sm[h] = sm[h] * cc + 1.f;
                w2a[h] = w2a[h] * cc + rm;
                Wa[h] = f4sfma(Wa[h], cc, rr, xa);
                Wb[h] = f4sfma(Wb[h], cc, rr, xc);
                mx[h] = s;
            }
        }
    }
    // ---- block combine ----
    float* lmx = lds; float* lsm = lds + 32; float* lw2 = lds + 64;
    if (lane == 0) {
#pragma unroll
        for (int h = 0; h < 4; ++h) {
            lmx[w * 4 + h] = mx[h];
            lsm[w * 4 + h] = sm[h];
            lw2[w * 4 + h] = w2a[h];
        }
    }
    __syncthreads();
    float bmx[4], f[4];
#pragma unroll
    for (int h = 0; h < 4; ++h) {
        float bm = lmx[h];
#pragma unroll
        for (int ww = 1; ww < 8; ++ww) bm = fmaxf(bm, lmx[ww * 4 + h]);
        bmx[h] = bm;
        f[h] = __expf(mx[h] - bm);
    }
    if (tid == 0) {
#pragma unroll
        for (int h = 0; h < 4; ++h) {
            float bs = 0.f, bw = 0.f;
            for (int ww = 0; ww < 8; ++ww) {
                float ff = __expf(lmx[ww * 4 + h] - bmx[h]);
                bs += lsm[ww * 4 + h] * ff;
                bw += lw2[ww * 4 + h] * ff;
            }
            ws[8192 + blockIdx.x * 4 + h] = bmx[h];
            ws[9216 + blockIdx.x * 4 + h] = bs;
            ws[10240 + blockIdx.x * 4 + h] = bw;
        }
    }
    __syncthreads();  // smalls consumed; safe to overwrite region 0
    float4* lw4 = (float4*)(lds + w * 2048);
#pragma unroll
    for (int h = 0; h < 4; ++h) {
        lw4[h * 128 + lane] = f4scale(Wa[h], f[h]);
        lw4[h * 128 + 64 + lane] = f4scale(Wb[h], f[h]);
    }
    __syncthreads();
    float* Wout = ws + 12288 + (size_t)blockIdx.x * 2048;
    for (int i = tid; i < 2048; i += 512) {
        float a = lds[i] + lds[2048 + i] + lds[4096 + i] + lds[6144 + i] +
                  lds[8192 + i] + lds[10240 + i] + lds[12288 + i] + lds[14336 + i];
        Wout[i] = a;
    }
}

// ---------- C0: global softmax stats across 256 block partials ----------
__global__ __launch_bounds__(256) void kC0(float* __restrict__ ws) {
    __shared__ float red[256];
    int tid = threadIdx.x;
    for (int h = 0; h < 4; ++h) {
        float vm = ws[8192 + tid * 4 + h];
        float vs = ws[9216 + tid * 4 + h];
        float vw = ws[10240 + tid * 4 + h];
        red[tid] = vm; __syncthreads();
        for (int s = 128; s; s >>= 1) {
            if (tid < s) red[tid] = fmaxf(red[tid], red[tid + s]);
            __syncthreads();
        }
        float bm = red[0]; __syncthreads();
        float ff = __expf(vm - bm);
        red[tid] = vs * ff; __syncthreads();
        for (int s = 128; s; s >>= 1) {
            if (tid < s) red[tid] += red[tid + s];
            __syncthreads();
        }
        float smg = red[0]; __syncthreads();
        red[tid] = vw * ff; __syncthreads();
        for (int s = 128; s; s >>= 1) {
            if (tid < s) red[tid] += red[tid + s];
            __syncthreads();
        }
        float w2g = red[0]; __syncthreads();
        if (tid == 0) {
            ws[2564 + h] = bm;
            ws[2568 + h] = 1.f / smg;
            ws[2572 + h] = w2g / smg;
        }
    }
}

// ---------- C1: c[h][e] = g1[e]*(W1g[h][e]/sm - W2g/sm) + be1[e] ----------
__global__ __launch_bounds__(256) void kC1(const float* __restrict__ g1,
                                           const float* __restrict__ be1,
                                           float* __restrict__ ws) {
    __shared__ float ef[256];
    int tid = threadIdx.x;
    int t = blockIdx.x * 256 + tid;
    int h = t >> 9, e = t & 511;
    ef[tid] = __expf(ws[8192 + tid * 4 + h] - ws[2564 + h]);
    __syncthreads();
    const float* Wb = ws + 12288 + h * 512 + e;
    float acc = 0.f;
#pragma unroll 8
    for (int b = 0; b < 256; ++b) acc += Wb[(size_t)b * 2048] * ef[b];
    float cv = g1[e] * (acc * ws[2568 + h] - ws[2572 + h]) + be1[e];
    ws[2576 + t] = cv;
}

// ---------- D1: o[j] = dot(Wv[j], c[h_j]) + bv[j]  (wave per j) ----------
__global__ __launch_bounds__(256) void kD1(const float* __restrict__ w_in,
                                           const float* __restrict__ b_in,
                                           float* __restrict__ ws) {
    int lane = threadIdx.x & 63;
    int j = blockIdx.x * 4 + (threadIdx.x >> 6);
    const float4* wr = (const float4*)(w_in + (size_t)(2 * DD + j) * DD);
    const float4* cr = (const float4*)(ws + 2576 + (j >> 7) * 512);
    float acc = dot4(wr[lane], cr[lane]) + dot4(wr[64 + lane], cr[64 + lane]);
    acc = wred(acc);
    if (lane == 0) ws[4624 + j] = acc + b_in[2 * DD + j];
}

// ---------- D2: y[i] = x0[i] + dot(w_out[i], o) + b_out[i] ----------
__global__ __launch_bounds__(256) void kD2(const float* __restrict__ x,
                                           const float* __restrict__ w_out,
                                           const float* __restrict__ b_out,
                                           float* __restrict__ ws) {
    int lane = threadIdx.x & 63;
    int j = blockIdx.x * 4 + (threadIdx.x >> 6);
    const float4* wr = (const float4*)(w_out + (size_t)j * DD);
    const float4* o4 = (const float4*)(ws + 4624);
    float acc = dot4(wr[lane], o4[lane]) + dot4(wr[64 + lane], o4[64 + lane]);
    acc = wred(acc);
    if (lane == 0) ws[5136 + j] = x[j] + acc + b_out[j];
}

// ---------- D2b: LN2 stats of y ----------
__global__ __launch_bounds__(512) void kD2b(float* __restrict__ ws) {
    __shared__ float red[512];
    int tid = threadIdx.x;
    float v = ws[5136 + tid];
    red[tid] = v; __syncthreads();
    for (int s = 256; s; s >>= 1) {
        if (tid < s) red[tid] += red[tid + s];
        __syncthreads();
    }
    float m = red[0] * (1.f / 512.f);
    __syncthreads();
    red[tid] = v * v; __syncthreads();
    for (int s = 256; s; s >>= 1) {
        if (tid < s) red[tid] += red[tid + s];
        __syncthreads();
    }
    float var = red[0] * (1.f / 512.f) - m * m;
    if (tid == 0) { ws[5648] = m; ws[5649] = rsqrtf(var + 1e-5f); }
}

// ---------- D3: h1[j] = relu(dot(w1[j], LN(y)) + b1[j]) ----------
__global__ __launch_bounds__(256) void kD3(const float* __restrict__ w1,
                                           const float* __restrict__ b1,
                                           const float* __restrict__ g2,
                                           const float* __restrict__ be2,
                                           float* __restrict__ ws) {
    int lane = threadIdx.x & 63;
    int j = blockIdx.x * 4 + (threadIdx.x >> 6);
    float m2 = ws[5648], r2 = ws[5649];
    const float4* y4 = (const float4*)(ws + 5136);
    const float4* g4 = (const float4*)g2;
    const float4* b4 = (const float4*)be2;
    float4 yna = lnrm4(y4[lane], m2, r2, g4[lane], b4[lane]);
    float4 ynb = lnrm4(y4[64 + lane], m2, r2, g4[64 + lane], b4[64 + lane]);
    const float4* wr = (const float4*)(w1 + (size_t)j * DD);
    float acc = dot4(wr[lane], yna) + dot4(wr[64 + lane], ynb);
    acc = wred(acc);
    if (lane == 0) ws[5664 + j] = fmaxf(acc + b1[j], 0.f);
}

// ---------- D4: out[j] = y[j] + dot(w2[j], h1) + b2[j] ----------
__global__ __launch_bounds__(256) void kD4(const float* __restrict__ w2,
                                           const float* __restrict__ b2,
                                           const float* __restrict__ ws,
                                           float* __restrict__ out) {
    int lane = threadIdx.x & 63;
    int j = blockIdx.x * 4 + (threadIdx.x >> 6);
    const float4* h4 = (const float4*)(ws + 5664);
    const float4* wr = (const float4*)(w2 + (size_t)j * DD);
    float acc = dot4(wr[lane], h4[lane]) + dot4(wr[64 + lane], h4[64 + lane]);
    acc = wred(acc);
    if (lane == 0) out[j] = ws[5136 + j] + acc + b2[j];
}

extern "C" void kernel_launch(void* const* d_in, const int* in_sizes, int n_in,
                              void* d_out, int out_size, void* d_ws, size_t ws_size,
                              hipStream_t stream) {
    (void)in_sizes; (void)n_in; (void)out_size; (void)ws_size;
    const float* x = (const float*)d_in[0];
    const float* w_in = (const float*)d_in[1];
    const float* b_in = (const float*)d_in[2];
    const float* w_out = (const float*)d_in[3];
    const float* b_out = (const float*)d_in[4];
    const float* w1 = (const float*)d_in[5];
    const float* b1 = (const float*)d_in[6];
    const float* w2 = (const float*)d_in[7];
    const float* b2 = (const float*)d_in[8];
    const float* g1 = (const float*)d_in[9];
    const float* be1 = (const float*)d_in[10];
    const float* g2 = (const float*)d_in[11];
    const float* be2 = (const float*)d_in[12];
    float* ws = (float*)d_ws;
    float* out = (float*)d_out;

    hipLaunchKernelGGL(kA1, dim3(128), dim3(256), 0, stream, x, w_in, b_in, g1, be1, ws);
    hipLaunchKernelGGL(kA2, dim3(4), dim3(512), 0, stream, w_in, g1, ws);
    hipLaunchKernelGGL(kB, dim3(256), dim3(512), 0, stream, x, ws);
    hipLaunchKernelGGL(kC0, dim3(1), dim3(256), 0, stream, ws);
    hipLaunchKernelGGL(kC1, dim3(8), dim3(256), 0, stream, g1, be1, ws);
    hipLaunchKernelGGL(kD1, dim3(128), dim3(256), 0, stream, w_in, b_in, ws);
    hipLaunchKernelGGL(kD2, dim3(128), dim3(256), 0, stream, x, w_out, b_out, ws);
    hipLaunchKernelGGL(kD2b, dim3(1), dim3(512), 0, stream, ws);
    hipLaunchKernelGGL(kD3, dim3(128), dim3(256), 0, stream, w1, b1, g2, be2, ws);
    hipLaunchKernelGGL(kD4, dim3(128), dim3(256), 0, stream, w2, b2, ws, out);
}

// Round 2
// 239.093 us; speedup vs baseline: 1.1764x; 1.1764x over previous
//
#include <hip/hip_runtime.h>
#include <math.h>

#define LL 65536
#define DD 512
#define NH 4
#define HDIM 128

// ---------- workspace layout (float offsets) ----------
// 0     : q[512]
// 1024  : p[4][4][512]   qk partials: chunk c, head h, col e  (raw, unscaled)
// 9216  : c_raw[2048]    attention-weighted xn context, raw (atomic-accumulated)
// 11264 : o[512]         attention output
// 11776 : y[512]         residual row
// 12288 : h1[512]        MLP hidden
// 16384 : sm_b[512][4]   per-kB-block softmax denominators (no max shift)
// 18432 : w2_b[512][4]   per-kB-block weighted rm sums
// 20480 : W1_b[512][2048] per-kB-block weighted-x partials (4 MB)

__device__ __forceinline__ float dot4(float4 a, float4 b) {
    return a.x * b.x + a.y * b.y + a.z * b.z + a.w * b.w;
}
__device__ __forceinline__ float wred(float v) {
#pragma unroll
    for (int m = 32; m; m >>= 1) v += __shfl_xor(v, m, 64);
    return v;
}
__device__ __forceinline__ float4 f4fma(float4 acc, float s, float4 v) {
    acc.x += s * v.x; acc.y += s * v.y; acc.z += s * v.z; acc.w += s * v.w;
    return acc;
}
__device__ __forceinline__ float4 f4add(float4 a, float4 b) {
    a.x += b.x; a.y += b.y; a.z += b.z; a.w += b.w; return a;
}
__device__ __forceinline__ float4 f4muls(float4 a, float4 g, float s) {
    a.x *= g.x * s; a.y *= g.y * s; a.z *= g.z * s; a.w *= g.w * s; return a;
}
__device__ __forceinline__ float hsum4(float4 a) { return a.x + a.y + a.z + a.w; }
__device__ __forceinline__ float4 lnrm4(float4 v, float m, float r, float4 g, float4 b) {
    float4 o;
    o.x = (v.x - m) * r * g.x + b.x; o.y = (v.y - m) * r * g.y + b.y;
    o.z = (v.z - m) * r * g.z + b.z; o.w = (v.w - m) * r * g.w + b.w;
    return o;
}
// c[e] = g[e]*(craw[e]*inv - w2t) + be[e]
__device__ __forceinline__ float4 caff4(float4 c, float inv, float w2t, float4 g, float4 b) {
    float4 o;
    o.x = g.x * (c.x * inv - w2t) + b.x; o.y = g.y * (c.y * inv - w2t) + b.y;
    o.z = g.z * (c.z * inv - w2t) + b.z; o.w = g.w * (c.w * inv - w2t) + b.w;
    return o;
}

// ---------- A1: q[j] = dot(Wq[j], LN(x0)) + bq[j]   (wave per j, 128 blocks) ----------
__global__ __launch_bounds__(256) void kA1(const float* __restrict__ x,
                                           const float* __restrict__ w_in,
                                           const float* __restrict__ b_in,
                                           const float* __restrict__ g1,
                                           const float* __restrict__ be1,
                                           float* __restrict__ ws) {
    int lane = threadIdx.x & 63;
    int j = blockIdx.x * 4 + (threadIdx.x >> 6);
    const float4* x4 = (const float4*)x;
    float4 a = x4[lane], b = x4[64 + lane];
    float ps = hsum4(a) + hsum4(b);
    float pss = dot4(a, a) + dot4(b, b);
    ps = wred(ps); pss = wred(pss);
    float m = ps * (1.f / 512.f);
    float r = rsqrtf(pss * (1.f / 512.f) - m * m + 1e-5f);
    const float4* g4 = (const float4*)g1;
    const float4* bb4 = (const float4*)be1;
    float4 xna = lnrm4(a, m, r, g4[lane], bb4[lane]);
    float4 xnb = lnrm4(b, m, r, g4[64 + lane], bb4[64 + lane]);
    const float4* wr = (const float4*)(w_in + (size_t)j * DD);
    float acc = dot4(wr[lane], xna) + dot4(wr[64 + lane], xnb);
    acc = wred(acc);
    if (lane == 0) ws[j] = acc + b_in[j];
}

// ---------- A2: p[c][h][e] = sum_{d in chunk c} q[h,d]*Wk[h*128+d, e]  (16 blocks) ----------
// also zero-inits c_raw (poisoned 0xAA every call)
__global__ __launch_bounds__(512) void kA2(const float* __restrict__ w_in,
                                           float* __restrict__ ws) {
    __shared__ float qh[32];
    int bi = blockIdx.x, tid = threadIdx.x;
    int h = bi >> 2, c = bi & 3;
    if (tid < 32) qh[tid] = ws[h * HDIM + c * 32 + tid];
    if (tid < 128) ws[9216 + bi * 128 + tid] = 0.f;
    __syncthreads();
    const float* wk = w_in + (size_t)(DD + h * HDIM + c * 32) * DD + tid;
    float acc = 0.f;
#pragma unroll
    for (int d = 0; d < 32; ++d) acc += qh[d] * wk[(size_t)d * DD];
    ws[1024 + c * 2048 + h * 512 + tid] = acc;
}

// ---------- B: streaming pass over x; shift-free softmax accumulation ----------
// 512 blocks x 512 threads, 16 rows/wave
__global__ __launch_bounds__(512) void kB(const float* __restrict__ x,
                                          const float* __restrict__ g1,
                                          float* __restrict__ ws) {
    __shared__ float lds[16384];  // 64 KB
    int tid = threadIdx.x, lane = tid & 63, w = tid >> 6;
    const float4* p4 = (const float4*)(ws + 1024);
    const float4* g4 = (const float4*)g1;
    const float scale = 0.088388347648318447f;  // 1/sqrt(128)
    float4 ga = g4[lane], gb = g4[64 + lane];
    float4 qa[4], qb[4];
    float qs[4];
#pragma unroll
    for (int h = 0; h < 4; ++h) {
        float4 sa = f4add(f4add(p4[h * 128 + lane], p4[512 + h * 128 + lane]),
                          f4add(p4[1024 + h * 128 + lane], p4[1536 + h * 128 + lane]));
        float4 sb = f4add(f4add(p4[h * 128 + 64 + lane], p4[512 + h * 128 + 64 + lane]),
                          f4add(p4[1024 + h * 128 + 64 + lane], p4[1536 + h * 128 + 64 + lane]));
        qa[h] = f4muls(sa, ga, scale);
        qb[h] = f4muls(sb, gb, scale);
        qs[h] = wred(hsum4(qa[h]) + hsum4(qb[h]));
    }
    float sm[4], w2a[4];
    float4 Wa[4], Wb[4];
#pragma unroll
    for (int h = 0; h < 4; ++h) {
        sm[h] = 0.f; w2a[h] = 0.f;
        Wa[h] = make_float4(0.f, 0.f, 0.f, 0.f);
        Wb[h] = make_float4(0.f, 0.f, 0.f, 0.f);
    }
    size_t row0 = ((size_t)blockIdx.x * 8 + w) * 16;
    const float4* xb = (const float4*)x + row0 * 128;
    float4 nxa = xb[lane], nxc = xb[64 + lane];
    for (int r = 0; r < 16; ++r) {
        float4 xa = nxa, xc = nxc;
        if (r < 15) { nxa = xb[(r + 1) * 128 + lane]; nxc = xb[(r + 1) * 128 + 64 + lane]; }
        float ps = hsum4(xa) + hsum4(xc);
        float pss = dot4(xa, xa) + dot4(xc, xc);
        float p0 = dot4(xa, qa[0]) + dot4(xc, qb[0]);
        float p1 = dot4(xa, qa[1]) + dot4(xc, qb[1]);
        float p2 = dot4(xa, qa[2]) + dot4(xc, qb[2]);
        float p3 = dot4(xa, qa[3]) + dot4(xc, qb[3]);
        ps = wred(ps); pss = wred(pss);
        p0 = wred(p0); p1 = wred(p1); p2 = wred(p2); p3 = wred(p3);
        float m = ps * (1.f / 512.f);
        float rr = rsqrtf(pss * (1.f / 512.f) - m * m + 1e-5f);
        float rm = rr * m;
        float pd[4] = {p0, p1, p2, p3};
#pragma unroll
        for (int h = 0; h < 4; ++h) {
            float s = rr * pd[h] - rm * qs[h];   // scores ~ O(1): exp never overflows
            float p = __expf(s);
            sm[h] += p;
            w2a[h] += p * rm;
            float pr = p * rr;
            Wa[h] = f4fma(Wa[h], pr, xa);
            Wb[h] = f4fma(Wb[h], pr, xc);
        }
    }
    // ---- per-block stats combine (pure sums: no max shift) ----
    if (lane == 0) {
#pragma unroll
        for (int h = 0; h < 4; ++h) {
            lds[w * 4 + h] = sm[h];
            lds[32 + w * 4 + h] = w2a[h];
        }
    }
    __syncthreads();
    if (tid < 8) {
        int h = tid & 3;
        float a = 0.f;
        if (tid < 4) {
            for (int ww = 0; ww < 8; ++ww) a += lds[ww * 4 + h];
            ws[16384 + blockIdx.x * 4 + h] = a;
        } else {
            for (int ww = 0; ww < 8; ++ww) a += lds[32 + ww * 4 + h];
            ws[18432 + blockIdx.x * 4 + h] = a;
        }
    }
    __syncthreads();  // stats consumed; safe to overwrite lds front
    float4* lw4 = (float4*)(lds + w * 2048);
#pragma unroll
    for (int h = 0; h < 4; ++h) {
        lw4[h * 128 + lane] = Wa[h];
        lw4[h * 128 + 64 + lane] = Wb[h];
    }
    __syncthreads();
    float* Wout = ws + 20480 + (size_t)blockIdx.x * 2048;
    for (int i = tid; i < 2048; i += 512) {
        float a = lds[i] + lds[2048 + i] + lds[4096 + i] + lds[6144 + i] +
                  lds[8192 + i] + lds[10240 + i] + lds[12288 + i] + lds[14336 + i];
        Wout[i] = a;
    }
}

// ---------- C1: c_raw[col] += chunk-sum over 32 kB-blocks  (128 blocks) ----------
__global__ __launch_bounds__(256) void kC1(float* __restrict__ ws) {
    int g = blockIdx.x * 256 + threadIdx.x;
    int col = g & 2047, chunk = g >> 11;   // 16 chunks of 32 blocks
    const float* Wb = ws + 20480 + (size_t)chunk * 32 * 2048 + col;
    float acc = 0.f;
#pragma unroll 8
    for (int b = 0; b < 32; ++b) acc += Wb[(size_t)b * 2048];
    atomicAdd(&ws[9216 + col], acc);
}

// ---------- D1: o[j] = dot(Wv[j], c[h]) + bv[j]; per-block softmax-stat reduce ----------
__global__ __launch_bounds__(256) void kD1(const float* __restrict__ w_in,
                                           const float* __restrict__ b_in,
                                           const float* __restrict__ g1,
                                           const float* __restrict__ be1,
                                           float* __restrict__ ws) {
    __shared__ float sred[16];
    int tid = threadIdx.x, lane = tid & 63, w = tid >> 6;
    int j = blockIdx.x * 4 + w;
    int h = j >> 7;  // uniform per block (j spans 4 consecutive)
    float s1 = ws[16384 + tid * 4 + h] + ws[16384 + (tid + 256) * 4 + h];
    float s2 = ws[18432 + tid * 4 + h] + ws[18432 + (tid + 256) * 4 + h];
    s1 = wred(s1); s2 = wred(s2);
    if (lane == 0) { sred[w * 2] = s1; sred[w * 2 + 1] = s2; }
    __syncthreads();
    float smg = sred[0] + sred[2] + sred[4] + sred[6];
    float w2g = sred[1] + sred[3] + sred[5] + sred[7];
    float inv = 1.f / smg;
    float w2t = w2g * inv;
    const float4* cr = (const float4*)(ws + 9216 + h * 512);
    const float4* g14 = (const float4*)g1;
    const float4* be14 = (const float4*)be1;
    float4 ca = caff4(cr[lane], inv, w2t, g14[lane], be14[lane]);
    float4 cb = caff4(cr[64 + lane], inv, w2t, g14[64 + lane], be14[64 + lane]);
    const float4* wr = (const float4*)(w_in + (size_t)(2 * DD + j) * DD);
    float acc = dot4(wr[lane], ca) + dot4(wr[64 + lane], cb);
    acc = wred(acc);
    if (lane == 0) ws[11264 + j] = acc + b_in[2 * DD + j];
}

// ---------- D2: y[i] = x0[i] + dot(w_out[i], o) + b_out[i] ----------
__global__ __launch_bounds__(256) void kD2(const float* __restrict__ x,
                                           const float* __restrict__ w_out,
                                           const float* __restrict__ b_out,
                                           float* __restrict__ ws) {
    int lane = threadIdx.x & 63;
    int j = blockIdx.x * 4 + (threadIdx.x >> 6);
    const float4* wr = (const float4*)(w_out + (size_t)j * DD);
    const float4* o4 = (const float4*)(ws + 11264);
    float acc = dot4(wr[lane], o4[lane]) + dot4(wr[64 + lane], o4[64 + lane]);
    acc = wred(acc);
    if (lane == 0) ws[11776 + j] = x[j] + acc + b_out[j];
}

// ---------- D3: h1[j] = relu(dot(w1[j], LN(y)) + b1[j]); LN2 stats per-wave ----------
__global__ __launch_bounds__(256) void kD3(const float* __restrict__ w1,
                                           const float* __restrict__ b1,
                                           const float* __restrict__ g2,
                                           const float* __restrict__ be2,
                                           float* __restrict__ ws) {
    int lane = threadIdx.x & 63;
    int j = blockIdx.x * 4 + (threadIdx.x >> 6);
    const float4* y4 = (const float4*)(ws + 11776);
    float4 ya = y4[lane], yb = y4[64 + lane];
    float ps = hsum4(ya) + hsum4(yb);
    float pss = dot4(ya, ya) + dot4(yb, yb);
    ps = wred(ps); pss = wred(pss);
    float m2 = ps * (1.f / 512.f);
    float r2 = rsqrtf(pss * (1.f / 512.f) - m2 * m2 + 1e-5f);
    const float4* g4 = (const float4*)g2;
    const float4* b4 = (const float4*)be2;
    float4 yna = lnrm4(ya, m2, r2, g4[lane], b4[lane]);
    float4 ynb = lnrm4(yb, m2, r2, g4[64 + lane], b4[64 + lane]);
    const float4* wr = (const float4*)(w1 + (size_t)j * DD);
    float acc = dot4(wr[lane], yna) + dot4(wr[64 + lane], ynb);
    acc = wred(acc);
    if (lane == 0) ws[12288 + j] = fmaxf(acc + b1[j], 0.f);
}

// ---------- D4: out[j] = y[j] + dot(w2[j], h1) + b2[j] ----------
__global__ __launch_bounds__(256) void kD4(const float* __restrict__ w2,
                                           const float* __restrict__ b2,
                                           const float* __restrict__ ws,
                                           float* __restrict__ out) {
    int lane = threadIdx.x & 63;
    int j = blockIdx.x * 4 + (threadIdx.x >> 6);
    const float4* h4 = (const float4*)(ws + 12288);
    const float4* wr = (const float4*)(w2 + (size_t)j * DD);
    float acc = dot4(wr[lane], h4[lane]) + dot4(wr[64 + lane], h4[64 + lane]);
    acc = wred(acc);
    if (lane == 0) out[j] = ws[11776 + j] + acc + b2[j];
}

extern "C" void kernel_launch(void* const* d_in, const int* in_sizes, int n_in,
                              void* d_out, int out_size, void* d_ws, size_t ws_size,
                              hipStream_t stream) {
    (void)in_sizes; (void)n_in; (void)out_size; (void)ws_size;
    const float* x = (const float*)d_in[0];
    const float* w_in = (const float*)d_in[1];
    const float* b_in = (const float*)d_in[2];
    const float* w_out = (const float*)d_in[3];
    const float* b_out = (const float*)d_in[4];
    const float* w1 = (const float*)d_in[5];
    const float* b1 = (const float*)d_in[6];
    const float* w2 = (const float*)d_in[7];
    const float* b2 = (const float*)d_in[8];
    const float* g1 = (const float*)d_in[9];
    const float* be1 = (const float*)d_in[10];
    const float* g2 = (const float*)d_in[11];
    const float* be2 = (const float*)d_in[12];
    float* ws = (float*)d_ws;
    float* out = (float*)d_out;

    hipLaunchKernelGGL(kA1, dim3(128), dim3(256), 0, stream, x, w_in, b_in, g1, be1, ws);
    hipLaunchKernelGGL(kA2, dim3(16), dim3(512), 0, stream, w_in, ws);
    hipLaunchKernelGGL(kB, dim3(512), dim3(512), 0, stream, x, g1, ws);
    hipLaunchKernelGGL(kC1, dim3(128), dim3(256), 0, stream, ws);
    hipLaunchKernelGGL(kD1, dim3(128), dim3(256), 0, stream, w_in, b_in, g1, be1, ws);
    hipLaunchKernelGGL(kD2, dim3(128), dim3(256), 0, stream, x, w_out, b_out, ws);
    hipLaunchKernelGGL(kD3, dim3(128), dim3(256), 0, stream, w1, b1, g2, be2, ws);
    hipLaunchKernelGGL(kD4, dim3(128), dim3(256), 0, stream, w2, b2, ws, out);
}